// Round 14
// baseline (255.411 us; speedup 1.0000x reference)
//
#include <hip/hip_runtime.h>

constexpr int Bn = 4096;
constexpr int Dn = 256;
constexpr int Sn = 256;
constexpr int NITEMS = 100000;
constexpr int NBLK_SCAN = (NITEMS + 255) / 256;   // 391

typedef float f32x4 __attribute__((ext_vector_type(4)));   // nt-load capable

// ---------------------------------------------------------------------------
// feat_hist: f = uf_cat @ W^T + bias. 32x64 tile, grid 512 (2 blocks/CU),
// 256 threads, 2x4 micro-tile, BK=32. Fused item histogram (8 rows/block),
// cnt pre-zeroed by memset.
// ---------------------------------------------------------------------------
__global__ __launch_bounds__(256) void feat_hist(
    const float* __restrict__ uf, const float* __restrict__ priv,
    const float* __restrict__ W,  const float* __restrict__ bias,
    const int* __restrict__ need_replace, const int* __restrict__ user_sample_items,
    float* __restrict__ fout, int* __restrict__ cnt) {
  __shared__ float A_s[32][36];
  __shared__ float B_s[32][68];
  const int t = threadIdx.x;

  if (cnt != nullptr) {
#pragma unroll
    for (int it = 0; it < 8; ++it) {
      const int b = blockIdx.x * 8 + it;
      const int uid  = need_replace[b * 2];
      const int item = user_sample_items[(size_t)uid * Sn + t];
      atomicAdd(&cnt[item], 1);
    }
  }

  const int m0 = (blockIdx.x >> 2) * 32;
  const int n0 = (blockIdx.x & 3) * 64;
  const int tx = t & 15, ty = t >> 4;

  float acc[2][4];
#pragma unroll
  for (int i = 0; i < 2; ++i)
#pragma unroll
    for (int j = 0; j < 4; ++j) acc[i][j] = 0.f;

  float ra[4], rb[8];
#pragma unroll
  for (int p = 0; p < 4; ++p) {
    const int e = t + p * 256, kk = e & 31, m = e >> 5;
    ra[p] = uf[(size_t)(m0 + m) * 512 + kk];
  }
#pragma unroll
  for (int p = 0; p < 8; ++p) {
    const int e = t + p * 256, kk = e & 31, m = e >> 5;
    rb[p] = W[(size_t)(n0 + m) * 513 + kk];
  }

  for (int c = 0; c < 16; ++c) {
#pragma unroll
    for (int p = 0; p < 4; ++p) {
      const int e = t + p * 256, kk = e & 31, m = e >> 5;
      A_s[kk][m] = ra[p];
    }
#pragma unroll
    for (int p = 0; p < 8; ++p) {
      const int e = t + p * 256, kk = e & 31, m = e >> 5;
      B_s[kk][m] = rb[p];
    }
    __syncthreads();
    if (c < 15) {
      const int k0 = (c + 1) * 32;
#pragma unroll
      for (int p = 0; p < 4; ++p) {
        const int e = t + p * 256, kk = e & 31, m = e >> 5;
        ra[p] = uf[(size_t)(m0 + m) * 512 + k0 + kk];
      }
#pragma unroll
      for (int p = 0; p < 8; ++p) {
        const int e = t + p * 256, kk = e & 31, m = e >> 5;
        rb[p] = W[(size_t)(n0 + m) * 513 + k0 + kk];
      }
    }
#pragma unroll
    for (int kk = 0; kk < 32; ++kk) {
      const float a0 = A_s[kk][ty];
      const float a1 = A_s[kk][ty + 16];
      const float4 b4 = *(const float4*)&B_s[kk][tx * 4];
      acc[0][0] = fmaf(a0, b4.x, acc[0][0]);
      acc[0][1] = fmaf(a0, b4.y, acc[0][1]);
      acc[0][2] = fmaf(a0, b4.z, acc[0][2]);
      acc[0][3] = fmaf(a0, b4.w, acc[0][3]);
      acc[1][0] = fmaf(a1, b4.x, acc[1][0]);
      acc[1][1] = fmaf(a1, b4.y, acc[1][1]);
      acc[1][2] = fmaf(a1, b4.z, acc[1][2]);
      acc[1][3] = fmaf(a1, b4.w, acc[1][3]);
    }
    __syncthreads();
  }

  const float av0 = priv[m0 + ty];
  const float av1 = priv[m0 + ty + 16];
  float bv[4];
#pragma unroll
  for (int j = 0; j < 4; ++j) bv[j] = W[(size_t)(n0 + tx * 4 + j) * 513 + 512];
#pragma unroll
  for (int j = 0; j < 4; ++j) {
    acc[0][j] = fmaf(av0, bv[j], acc[0][j]);
    acc[1][j] = fmaf(av1, bv[j], acc[1][j]);
  }
  const float4 bb = *(const float4*)&bias[n0 + tx * 4];
  {
    float4 o;
    o.x = acc[0][0] + bb.x; o.y = acc[0][1] + bb.y;
    o.z = acc[0][2] + bb.z; o.w = acc[0][3] + bb.w;
    *(float4*)&fout[(size_t)(m0 + ty) * Dn + n0 + tx * 4] = o;
    o.x = acc[1][0] + bb.x; o.y = acc[1][1] + bb.y;
    o.z = acc[1][2] + bb.z; o.w = acc[1][3] + bb.w;
    *(float4*)&fout[(size_t)(m0 + ty + 16) * Dn + n0 + tx * 4] = o;
  }
}

// ---------------------------------------------------------------------------
// scan_a: block-local exclusive scan of cnt + per-block sums
// ---------------------------------------------------------------------------
__global__ __launch_bounds__(256) void scan_a(const int* __restrict__ cnt,
                                              int* __restrict__ offsets,
                                              int* __restrict__ blocksum) {
  __shared__ int s[256];
  const int tid = threadIdx.x;
  const int i = blockIdx.x * 256 + tid;
  const int v = (i < NITEMS) ? cnt[i] : 0;
  int x = v;
  s[tid] = x;
  __syncthreads();
  for (int d = 1; d < 256; d <<= 1) {
    const int add = (tid >= d) ? s[tid - d] : 0;
    __syncthreads();
    x += add;
    s[tid] = x;
    __syncthreads();
  }
  if (i < NITEMS) offsets[i] = x - v;
  if (tid == 255) blocksum[blockIdx.x] = x;
}

// ---------------------------------------------------------------------------
// scan_bc: block j sums blocksum[0..j) itself, finalizes offsets + cursor.
// ---------------------------------------------------------------------------
__global__ __launch_bounds__(256) void scan_bc(const int* __restrict__ blocksum,
                                               int* __restrict__ offsets,
                                               int* __restrict__ cursor) {
  __shared__ int red[4];
  const int tid = threadIdx.x, lane = tid & 63, w = tid >> 6;
  const int j = blockIdx.x;
  int part = 0;
  for (int i = tid; i < j; i += 256) part += blocksum[i];
#pragma unroll
  for (int off = 32; off; off >>= 1) part += __shfl_xor(part, off, 64);
  if (lane == 0) red[w] = part;
  __syncthreads();
  const int prefix = red[0] + red[1] + red[2] + red[3];
  const int i = j * 256 + tid;
  if (i < NITEMS) {
    const int o = offsets[i] + prefix;
    offsets[i] = o;
    cursor[i]  = o;
  }
}

// ---------------------------------------------------------------------------
// scatter8: emit (cid,item) int2 pairs grouped by item; 8 pairs/thread ->
// 8 independent atomic->store chains in flight; nt loads + nt stores.
// ---------------------------------------------------------------------------
__global__ __launch_bounds__(256) void scatter8(
    const int* __restrict__ need_replace, const int* __restrict__ user_sample_items,
    int* __restrict__ cursor, int2* __restrict__ pairs) {
  const int b0 = blockIdx.x * 8;
  const int t = threadIdx.x;
  int item[8], cid[8];
#pragma unroll
  for (int it = 0; it < 8; ++it) {
    const int b = b0 + it;
    const int uid = need_replace[b * 2];
    item[it] = __builtin_nontemporal_load(&user_sample_items[(size_t)uid * Sn + t]);
    cid[it]  = b * Sn + t;
  }
  int pos[8];
#pragma unroll
  for (int it = 0; it < 8; ++it) pos[it] = atomicAdd(&cursor[item[it]], 1);
#pragma unroll
  for (int it = 0; it < 8; ++it) {
    __builtin_nontemporal_store(cid[it],  &pairs[pos[it]].x);
    __builtin_nontemporal_store(item[it], &pairs[pos[it]].y);
  }
}

// ---------------------------------------------------------------------------
// score_sorted: 4096 blocks x 256 thr (4 waves); block owns 256 item-sorted
// (cid,item) pairs. Lean LDS (<19.6 KB) -> 8 blocks/CU. Single-touch streams
// (pairs, item rows) use nontemporal loads so the 102MB item stream does not
// evict the 4MB L2-resident f table -- f-loads stay L2 hits.
// 8-lane group per pair: f-row from global (contiguous 128B/group-instr),
// item row from LDS. Deterministic: score = g(cid,item) only.
// ---------------------------------------------------------------------------
constexpr int CH    = 256;
constexpr int CROWS = 16;
constexpr int RP    = Dn + 4;

__global__ __launch_bounds__(256) void score_sorted(
    const float* __restrict__ all_items, const float* __restrict__ f,
    const int2* __restrict__ pairs, float* __restrict__ scores) {
  __shared__ float rows[CROWS][RP];          // 16,640 B
  __shared__ int cid_s[CH];
  __shared__ unsigned char slot_s[CH];
  __shared__ short head_s[CH + 2];
  __shared__ int item_slot[CH];
  __shared__ int wsum[4];
  __shared__ int wlast[4];

  const int t = threadIdx.x, lane = t & 63, w = t >> 6;

  int2 pr;
  pr.x = __builtin_nontemporal_load(&pairs[(size_t)blockIdx.x * CH + t].x);
  pr.y = __builtin_nontemporal_load(&pairs[(size_t)blockIdx.x * CH + t].y);
  cid_s[t] = pr.x;
  if (lane == 63) wlast[w] = pr.y;
  __syncthreads();

  // run-head detection without an item_s array
  const int prev = (lane == 0) ? ((w == 0) ? -1 : wlast[w - 1])
                               : __shfl_up(pr.y, 1, 64);
  const int h = (t == 0 || pr.y != prev) ? 1 : 0;
  const unsigned long long mask = __ballot(h != 0);
  const int wc  = __popcll(mask);
  const int pre = __popcll(mask & ((1ull << lane) - 1ull));
  if (lane == 0) wsum[w] = wc;
  __syncthreads();
  int off0 = 0;
  for (int i = 0; i < w; ++i) off0 += wsum[i];
  const int k = wsum[0] + wsum[1] + wsum[2] + wsum[3];
  const int slot = off0 + pre + h - 1;
  slot_s[t] = (unsigned char)slot;
  if (h) {
    head_s[slot] = (short)t;
    item_slot[slot] = pr.y;
  }
  if (t == 0) head_s[k] = (short)CH;   // sentinel
  __syncthreads();

  const int gid = t >> 3, q = t & 7;

  for (int base = 0; base < k; base += CROWS) {
    const int nb = min(CROWS, k - base);
    if (base) __syncthreads();          // protect rows[] from prior readers
    if (gid < nb) {                     // groups 0..nb-1 stage one row each
      const float* src = &all_items[(size_t)item_slot[base + gid] * Dn + q * 4];
#pragma unroll
      for (int j = 0; j < 8; ++j) {
        const f32x4 v = __builtin_nontemporal_load((const f32x4*)&src[j * 32]);
        *(f32x4*)&rows[gid][q * 4 + j * 32] = v;
      }
    }
    __syncthreads();

    const int lo = head_s[base];
    const int hi = head_s[base + nb];   // sentinel covers base+nb == k
    for (int i = lo + gid; i < hi; i += 32) {
      const int cid = cid_s[i];
      const int sl  = (int)slot_s[i] - base;
      const float* fp = &f[(size_t)(cid >> 8) * Dn + q * 4];
      float4 fv[8];
#pragma unroll
      for (int j = 0; j < 8; ++j) fv[j] = *(const float4*)&fp[j * 32];
      __builtin_amdgcn_sched_barrier(0);
      float a0 = 0.f, a1 = 0.f;
#pragma unroll
      for (int j = 0; j < 8; j += 2) {
        const float4 r0 = *(const float4*)&rows[sl][q * 4 + j * 32];
        const float4 r1 = *(const float4*)&rows[sl][q * 4 + (j + 1) * 32];
        a0 = fmaf(fv[j].x, r0.x, a0);
        a0 = fmaf(fv[j].y, r0.y, a0);
        a0 = fmaf(fv[j].z, r0.z, a0);
        a0 = fmaf(fv[j].w, r0.w, a0);
        a1 = fmaf(fv[j + 1].x, r1.x, a1);
        a1 = fmaf(fv[j + 1].y, r1.y, a1);
        a1 = fmaf(fv[j + 1].z, r1.z, a1);
        a1 = fmaf(fv[j + 1].w, r1.w, a1);
      }
      float acc = a0 + a1;
      acc += __shfl_xor(acc, 1, 64);
      acc += __shfl_xor(acc, 2, 64);
      acc += __shfl_xor(acc, 4, 64);
      if (q == 0) scores[cid] = acc;
    }
  }
}

// ---------------------------------------------------------------------------
// finish: softmax + weighted index + compacted pass-2 (verified structure);
// compacted all_items gather rows are single-touch -> nontemporal.
// ---------------------------------------------------------------------------
__global__ __launch_bounds__(256) void finish_kernel(
    const int* __restrict__ need_replace, const int* __restrict__ user_sample_items,
    const float* __restrict__ scores, const float* __restrict__ all_items,
    float* __restrict__ out_items, float* __restrict__ feat_out,
    float* __restrict__ out_scalars) {
  __shared__ float red_s[8];
  __shared__ int   sel_idx[Sn];
  __shared__ float sel_p[Sn];
  __shared__ int   warp_cnt[4];

  const int b = blockIdx.x, t = threadIdx.x;
  const int lane = t & 63, w = t >> 6;
  const int uid = need_replace[b * 2];
  const int myitem = user_sample_items[(size_t)uid * Sn + t];
  const float v = scores[b * Sn + t];

  float m = v;
#pragma unroll
  for (int off = 32; off; off >>= 1) m = fmaxf(m, __shfl_xor(m, off, 64));
  if (lane == 0) red_s[w] = m;
  __syncthreads();
  m = fmaxf(fmaxf(red_s[0], red_s[1]), fmaxf(red_s[2], red_s[3]));

  const float e0 = expf(v - m);
  float ssum = e0;
#pragma unroll
  for (int off = 32; off; off >>= 1) ssum += __shfl_xor(ssum, off, 64);
  if (lane == 0) red_s[4 + w] = ssum;
  __syncthreads();
  const float tot = red_s[4] + red_s[5] + red_s[6] + red_s[7];
  const float p = e0 / tot;

  float ri = p * (float)myitem;
#pragma unroll
  for (int off = 32; off; off >>= 1) ri += __shfl_xor(ri, off, 64);
  if (lane == 0) red_s[w] = ri;

  const bool flag = (p >= 1e-7f);
  const unsigned long long mask = __ballot(flag);
  const int wc     = __popcll(mask);
  const int prefix = __popcll(mask & ((1ull << lane) - 1ull));
  if (lane == 0) warp_cnt[w] = wc;
  __syncthreads();

  if (t == 0) {
    const float tot_ri = red_s[0] + red_s[1] + red_s[2] + red_s[3];
    out_items[b] = (float)(int)tot_ri;
  }
  int off0 = 0;
  for (int i = 0; i < w; ++i) off0 += warp_cnt[i];
  const int nsel = warp_cnt[0] + warp_cnt[1] + warp_cnt[2] + warp_cnt[3];
  if (flag) {
    sel_idx[off0 + prefix] = myitem;
    sel_p[off0 + prefix]   = p;
  }
  __syncthreads();

  float acc = 0.f;
  for (int i = 0; i < nsel; ++i)
    acc += sel_p[i] * __builtin_nontemporal_load(&all_items[(size_t)sel_idx[i] * Dn + t]);
  feat_out[(size_t)b * Dn + t] = acc;

  if (b == 0 && t < 2) out_scalars[t] = 0.f;
}

// ---------------------------------------------------------------------------
// fold helper + fallback main kernel (round-2, verified) for small ws_size.
// ---------------------------------------------------------------------------
__device__ __forceinline__ float fold(float a, float b, int m, int lane) {
  const float keep = (lane & m) ? b : a;
  const float send = (lane & m) ? a : b;
  return keep + __shfl_xor(send, m, 64);
}

__global__ __launch_bounds__(256) void main_fb(
    const int* __restrict__ need_replace,
    const int* __restrict__ user_sample_items,
    const float* __restrict__ all_items,
    float* __restrict__ out_items, float* __restrict__ feat_io,
    float* __restrict__ out_scalars) {
  __shared__ __align__(16) float f_s[Dn];
  __shared__ int   items_s[Sn];
  __shared__ float red_s[8];
  __shared__ int   sel_idx[Sn];
  __shared__ float sel_p[Sn];
  __shared__ int   warp_cnt[4];

  const int b = blockIdx.x, t = threadIdx.x;
  const int lane = t & 63, w = t >> 6;
  const int uid = need_replace[b * 2];
  items_s[t] = user_sample_items[(size_t)uid * Sn + t];
  f_s[t]     = feat_io[(size_t)b * Dn + t];
  __syncthreads();

  const float4 fr = *(const float4*)&f_s[lane * 4];
  const int base = w * 64;
  float4 e[8];
#pragma unroll
  for (int j = 0; j < 8; ++j)
    e[j] = *(const float4*)&all_items[(size_t)items_s[base + 8 * j] * Dn + lane * 4];
  float grp[8];
#pragma unroll
  for (int c = 0; c < 8; ++c) {
    float p[8];
#pragma unroll
    for (int j = 0; j < 8; ++j) {
      const float4 ev = e[j];
      p[j] = fmaf(fr.x, ev.x, fmaf(fr.y, ev.y, fmaf(fr.z, ev.z, fr.w * ev.w)));
      if (c < 7)
        e[j] = *(const float4*)&all_items[(size_t)items_s[base + (c + 1) + 8 * j] * Dn + lane * 4];
    }
    const float q0 = fold(p[0], p[4], 32, lane), q1 = fold(p[1], p[5], 32, lane);
    const float q2 = fold(p[2], p[6], 32, lane), q3 = fold(p[3], p[7], 32, lane);
    const float r0 = fold(q0, q2, 16, lane),     r1 = fold(q1, q3, 16, lane);
    grp[c] = fold(r0, r1, 8, lane);
  }
  const float s0 = fold(grp[0], grp[4], 4, lane), s1 = fold(grp[1], grp[5], 4, lane);
  const float s2 = fold(grp[2], grp[6], 4, lane), s3 = fold(grp[3], grp[7], 4, lane);
  const float t0 = fold(s0, s2, 2, lane),         t1 = fold(s1, s3, 2, lane);
  const float v  = fold(t0, t1, 1, lane);

  float m = v;
#pragma unroll
  for (int off = 32; off; off >>= 1) m = fmaxf(m, __shfl_xor(m, off, 64));
  if (lane == 0) red_s[w] = m;
  __syncthreads();
  m = fmaxf(fmaxf(red_s[0], red_s[1]), fmaxf(red_s[2], red_s[3]));
  const float e0 = expf(v - m);
  float ssum = e0;
#pragma unroll
  for (int off = 32; off; off >>= 1) ssum += __shfl_xor(ssum, off, 64);
  if (lane == 0) red_s[4 + w] = ssum;
  __syncthreads();
  const float tot = red_s[4] + red_s[5] + red_s[6] + red_s[7];
  const float p = e0 / tot;
  float ri = p * (float)items_s[t];
#pragma unroll
  for (int off = 32; off; off >>= 1) ri += __shfl_xor(ri, off, 64);
  if (lane == 0) red_s[w] = ri;
  const bool flag = (p >= 1e-7f);
  const unsigned long long mask = __ballot(flag);
  const int wc = __popcll(mask);
  const int prefix = __popcll(mask & ((1ull << lane) - 1ull));
  if (lane == 0) warp_cnt[w] = wc;
  __syncthreads();
  if (t == 0) {
    const float tot_ri = red_s[0] + red_s[1] + red_s[2] + red_s[3];
    out_items[b] = (float)(int)tot_ri;
  }
  int off0 = 0;
  for (int i = 0; i < w; ++i) off0 += warp_cnt[i];
  const int nsel = warp_cnt[0] + warp_cnt[1] + warp_cnt[2] + warp_cnt[3];
  if (flag) {
    sel_idx[off0 + prefix] = items_s[t];
    sel_p[off0 + prefix]   = p;
  }
  __syncthreads();
  float acc = 0.f;
  for (int i = 0; i < nsel; ++i)
    acc += sel_p[i] * all_items[(size_t)sel_idx[i] * Dn + t];
  feat_io[(size_t)b * Dn + t] = acc;
  if (b == 0 && t < 2) out_scalars[t] = 0.f;
}

extern "C" void kernel_launch(void* const* d_in, const int* in_sizes, int n_in,
                              void* d_out, int out_size, void* d_ws, size_t ws_size,
                              hipStream_t stream) {
  const int*   need_replace      = (const int*)d_in[0];
  const float* union_feature     = (const float*)d_in[1];
  const float* all_items         = (const float*)d_in[2];
  const float* privacy_settings  = (const float*)d_in[3];
  const int*   user_sample_items = (const int*)d_in[4];
  const float* W                 = (const float*)d_in[5];
  const float* bias              = (const float*)d_in[6];

  float* out       = (float*)d_out;
  float* out_items = out;
  float* feat_io   = out + Bn;                     // f, then feature out
  float* out_scal  = out + Bn + (size_t)Bn * Dn;

  const size_t NEED = (size_t)1048576 * 8          // pairs (int2)
                    + (size_t)1048576 * 4          // scores
                    + (size_t)3 * NITEMS * 4 + 512 * 4;
  int2*  pairs    = (int2*)d_ws;
  float* scores   = (float*)(pairs + 1048576);
  int*   cnt      = (int*)(scores + 1048576);
  int*   offsets  = cnt + NITEMS;
  int*   cursor   = offsets + NITEMS;
  int*   blocksum = cursor + NITEMS;

  if (ws_size >= NEED) {
    (void)hipMemsetAsync(cnt, 0, NITEMS * sizeof(int), stream);
    feat_hist<<<512, 256, 0, stream>>>(union_feature, privacy_settings, W, bias,
                                       need_replace, user_sample_items,
                                       feat_io, cnt);
    scan_a<<<NBLK_SCAN, 256, 0, stream>>>(cnt, offsets, blocksum);
    scan_bc<<<NBLK_SCAN, 256, 0, stream>>>(blocksum, offsets, cursor);
    scatter8<<<Bn / 8, 256, 0, stream>>>(need_replace, user_sample_items,
                                         cursor, pairs);
    score_sorted<<<1048576 / CH, 256, 0, stream>>>(all_items, feat_io, pairs,
                                                   scores);
    finish_kernel<<<Bn, 256, 0, stream>>>(need_replace, user_sample_items, scores,
                                          all_items, out_items, feat_io, out_scal);
  } else {
    feat_hist<<<512, 256, 0, stream>>>(union_feature, privacy_settings, W, bias,
                                       need_replace, user_sample_items,
                                       feat_io, nullptr);
    main_fb<<<Bn, 256, 0, stream>>>(need_replace, user_sample_items, all_items,
                                    out_items, feat_io, out_scal);
  }
}

// Round 15
// 180.875 us; speedup vs baseline: 1.4121x; 1.4121x over previous
//
#include <hip/hip_runtime.h>

constexpr int Bn = 4096;
constexpr int Dn = 256;
constexpr int Sn = 256;

// ---------------------------------------------------------------------------
// feat_v4: f[4096][256] = uf_cat[4096][513] @ W^T + bias.
// 32x64 tile, grid 512 (2 blocks/CU), 256 threads, 2x4 micro-tile, BK=32,
// register-prefetch double-staging. (R9 feat_hist minus the histogram --
// GEMM path verified R9-R14.)
// ---------------------------------------------------------------------------
__global__ __launch_bounds__(256) void feat_v4(
    const float* __restrict__ uf, const float* __restrict__ priv,
    const float* __restrict__ W,  const float* __restrict__ bias,
    float* __restrict__ fout) {
  __shared__ float A_s[32][36];
  __shared__ float B_s[32][68];
  const int t = threadIdx.x;

  const int m0 = (blockIdx.x >> 2) * 32;
  const int n0 = (blockIdx.x & 3) * 64;
  const int tx = t & 15, ty = t >> 4;

  float acc[2][4];
#pragma unroll
  for (int i = 0; i < 2; ++i)
#pragma unroll
    for (int j = 0; j < 4; ++j) acc[i][j] = 0.f;

  float ra[4], rb[8];
#pragma unroll
  for (int p = 0; p < 4; ++p) {
    const int e = t + p * 256, kk = e & 31, m = e >> 5;
    ra[p] = uf[(size_t)(m0 + m) * 512 + kk];
  }
#pragma unroll
  for (int p = 0; p < 8; ++p) {
    const int e = t + p * 256, kk = e & 31, m = e >> 5;
    rb[p] = W[(size_t)(n0 + m) * 513 + kk];
  }

  for (int c = 0; c < 16; ++c) {
#pragma unroll
    for (int p = 0; p < 4; ++p) {
      const int e = t + p * 256, kk = e & 31, m = e >> 5;
      A_s[kk][m] = ra[p];
    }
#pragma unroll
    for (int p = 0; p < 8; ++p) {
      const int e = t + p * 256, kk = e & 31, m = e >> 5;
      B_s[kk][m] = rb[p];
    }
    __syncthreads();
    if (c < 15) {
      const int k0 = (c + 1) * 32;
#pragma unroll
      for (int p = 0; p < 4; ++p) {
        const int e = t + p * 256, kk = e & 31, m = e >> 5;
        ra[p] = uf[(size_t)(m0 + m) * 512 + k0 + kk];
      }
#pragma unroll
      for (int p = 0; p < 8; ++p) {
        const int e = t + p * 256, kk = e & 31, m = e >> 5;
        rb[p] = W[(size_t)(n0 + m) * 513 + k0 + kk];
      }
    }
#pragma unroll
    for (int kk = 0; kk < 32; ++kk) {
      const float a0 = A_s[kk][ty];
      const float a1 = A_s[kk][ty + 16];
      const float4 b4 = *(const float4*)&B_s[kk][tx * 4];
      acc[0][0] = fmaf(a0, b4.x, acc[0][0]);
      acc[0][1] = fmaf(a0, b4.y, acc[0][1]);
      acc[0][2] = fmaf(a0, b4.z, acc[0][2]);
      acc[0][3] = fmaf(a0, b4.w, acc[0][3]);
      acc[1][0] = fmaf(a1, b4.x, acc[1][0]);
      acc[1][1] = fmaf(a1, b4.y, acc[1][1]);
      acc[1][2] = fmaf(a1, b4.z, acc[1][2]);
      acc[1][3] = fmaf(a1, b4.w, acc[1][3]);
    }
    __syncthreads();
  }

  // k = 512 tail (privacy column) + bias
  const float av0 = priv[m0 + ty];
  const float av1 = priv[m0 + ty + 16];
  float bv[4];
#pragma unroll
  for (int j = 0; j < 4; ++j) bv[j] = W[(size_t)(n0 + tx * 4 + j) * 513 + 512];
#pragma unroll
  for (int j = 0; j < 4; ++j) {
    acc[0][j] = fmaf(av0, bv[j], acc[0][j]);
    acc[1][j] = fmaf(av1, bv[j], acc[1][j]);
  }
  const float4 bb = *(const float4*)&bias[n0 + tx * 4];
  {
    float4 o;
    o.x = acc[0][0] + bb.x; o.y = acc[0][1] + bb.y;
    o.z = acc[0][2] + bb.z; o.w = acc[0][3] + bb.w;
    *(float4*)&fout[(size_t)(m0 + ty) * Dn + n0 + tx * 4] = o;
    o.x = acc[1][0] + bb.x; o.y = acc[1][1] + bb.y;
    o.z = acc[1][2] + bb.z; o.w = acc[1][3] + bb.w;
    *(float4*)&fout[(size_t)(m0 + ty + 16) * Dn + n0 + tx * 4] = o;
  }
}

// ---------------------------------------------------------------------------
// fold: R2-verified family merge across lane bit m. After folds 32,16,8 and
// cross-group folds 4,2,1 over p[0..7] x groups, lane l holds value s=l.
// ---------------------------------------------------------------------------
__device__ __forceinline__ float fold(float a, float b, int m, int lane) {
  const float keep = (lane & m) ? b : a;
  const float send = (lane & m) ? a : b;
  return keep + __shfl_xor(send, m, 64);
}

// ---------------------------------------------------------------------------
// main_fb (R2-verified, byte-identical): 4096 blocks x 256 thr (4 waves).
// Wave w scores s in [w*64, w*64+64): 8 wave-wide float4 gathers in flight,
// batched fold-tree reduction; softmax; weighted item index; second einsum
// over ballot-compacted s with p >= 1e-7. Runs at the random-line fabric
// ceiling (522 MB @ ~3.4 TB/s).
// ---------------------------------------------------------------------------
__global__ __launch_bounds__(256) void main_fb(
    const int* __restrict__ need_replace,
    const int* __restrict__ user_sample_items,
    const float* __restrict__ all_items,
    float* __restrict__ out_items, float* __restrict__ feat_io,
    float* __restrict__ out_scalars) {
  __shared__ __align__(16) float f_s[Dn];
  __shared__ int   items_s[Sn];
  __shared__ float red_s[8];
  __shared__ int   sel_idx[Sn];
  __shared__ float sel_p[Sn];
  __shared__ int   warp_cnt[4];

  const int b = blockIdx.x, t = threadIdx.x;
  const int lane = t & 63, w = t >> 6;
  const int uid = need_replace[b * 2];
  items_s[t] = user_sample_items[(size_t)uid * Sn + t];
  f_s[t]     = feat_io[(size_t)b * Dn + t];
  __syncthreads();

  const float4 fr = *(const float4*)&f_s[lane * 4];
  const int base = w * 64;
  float4 e[8];
#pragma unroll
  for (int j = 0; j < 8; ++j)
    e[j] = *(const float4*)&all_items[(size_t)items_s[base + 8 * j] * Dn + lane * 4];
  float grp[8];
#pragma unroll
  for (int c = 0; c < 8; ++c) {
    float p[8];
#pragma unroll
    for (int j = 0; j < 8; ++j) {
      const float4 ev = e[j];
      p[j] = fmaf(fr.x, ev.x, fmaf(fr.y, ev.y, fmaf(fr.z, ev.z, fr.w * ev.w)));
      if (c < 7)
        e[j] = *(const float4*)&all_items[(size_t)items_s[base + (c + 1) + 8 * j] * Dn + lane * 4];
    }
    const float q0 = fold(p[0], p[4], 32, lane), q1 = fold(p[1], p[5], 32, lane);
    const float q2 = fold(p[2], p[6], 32, lane), q3 = fold(p[3], p[7], 32, lane);
    const float r0 = fold(q0, q2, 16, lane),     r1 = fold(q1, q3, 16, lane);
    grp[c] = fold(r0, r1, 8, lane);
  }
  const float s0 = fold(grp[0], grp[4], 4, lane), s1 = fold(grp[1], grp[5], 4, lane);
  const float s2 = fold(grp[2], grp[6], 4, lane), s3 = fold(grp[3], grp[7], 4, lane);
  const float t0 = fold(s0, s2, 2, lane),         t1 = fold(s1, s3, 2, lane);
  const float v  = fold(t0, t1, 1, lane);   // lane l holds score for s = base+l

  float m = v;
#pragma unroll
  for (int off = 32; off; off >>= 1) m = fmaxf(m, __shfl_xor(m, off, 64));
  if (lane == 0) red_s[w] = m;
  __syncthreads();
  m = fmaxf(fmaxf(red_s[0], red_s[1]), fmaxf(red_s[2], red_s[3]));
  const float e0 = expf(v - m);
  float ssum = e0;
#pragma unroll
  for (int off = 32; off; off >>= 1) ssum += __shfl_xor(ssum, off, 64);
  if (lane == 0) red_s[4 + w] = ssum;
  __syncthreads();
  const float tot = red_s[4] + red_s[5] + red_s[6] + red_s[7];
  const float p = e0 / tot;
  float ri = p * (float)items_s[t];
#pragma unroll
  for (int off = 32; off; off >>= 1) ri += __shfl_xor(ri, off, 64);
  if (lane == 0) red_s[w] = ri;
  const bool flag = (p >= 1e-7f);
  const unsigned long long mask = __ballot(flag);
  const int wc = __popcll(mask);
  const int prefix = __popcll(mask & ((1ull << lane) - 1ull));
  if (lane == 0) warp_cnt[w] = wc;
  __syncthreads();
  if (t == 0) {
    const float tot_ri = red_s[0] + red_s[1] + red_s[2] + red_s[3];
    out_items[b] = (float)(int)tot_ri;   // astype(int32) truncation
  }
  int off0 = 0;
  for (int i = 0; i < w; ++i) off0 += warp_cnt[i];
  const int nsel = warp_cnt[0] + warp_cnt[1] + warp_cnt[2] + warp_cnt[3];
  if (flag) {
    sel_idx[off0 + prefix] = items_s[t];
    sel_p[off0 + prefix]   = p;
  }
  __syncthreads();
  float acc = 0.f;
  for (int i = 0; i < nsel; ++i)
    acc += sel_p[i] * all_items[(size_t)sel_idx[i] * Dn + t];
  feat_io[(size_t)b * Dn + t] = acc;
  if (b == 0 && t < 2) out_scalars[t] = 0.f;
}

extern "C" void kernel_launch(void* const* d_in, const int* in_sizes, int n_in,
                              void* d_out, int out_size, void* d_ws, size_t ws_size,
                              hipStream_t stream) {
  const int*   need_replace      = (const int*)d_in[0];
  const float* union_feature     = (const float*)d_in[1];
  const float* all_items         = (const float*)d_in[2];
  const float* privacy_settings  = (const float*)d_in[3];
  const int*   user_sample_items = (const int*)d_in[4];
  const float* W                 = (const float*)d_in[5];
  const float* bias              = (const float*)d_in[6];

  float* out       = (float*)d_out;
  float* out_items = out;                          // Bn
  float* feat_io   = out + Bn;                     // Bn*Dn: f in, feature out
  float* out_scal  = out + Bn + (size_t)Bn * Dn;   // 2 scalars

  feat_v4<<<512, 256, 0, stream>>>(union_feature, privacy_settings, W, bias,
                                   feat_io);
  main_fb<<<Bn, 256, 0, stream>>>(need_replace, user_sample_items, all_items,
                                  out_items, feat_io, out_scal);
}